// Round 6
// baseline (183.797 us; speedup 1.0000x reference)
//
#include <hip/hip_runtime.h>
#include <math.h>

#define IN_CH 128
#define OUT_CH 64
#define NEG_SLOPE 0.2f
#define CAP 64           // slots per node; mean degree 16, P(deg>64) ~ 1e-16
#define NSHARD 8         // = XCD count
#define CHUNK_EDGES 4096 // edges per block/chunk (256 thr x 16)

typedef long long ll2 __attribute__((ext_vector_type(2)));
typedef int i4v __attribute__((ext_vector_type(4)));
typedef float f4v __attribute__((ext_vector_type(4)));
typedef unsigned short us4v __attribute__((ext_vector_type(4)));

// ---------- bf16 helpers ----------
__device__ __forceinline__ unsigned short f2bf(float f) {
    unsigned u = __float_as_uint(f);
    unsigned r = (u + 0x7FFFu + ((u >> 16) & 1u)) >> 16;   // round-nearest-even
    return (unsigned short)r;
}

// ---------- edge dtype sniff: int64 little-endian => odd int32 words are 0 ----------
__device__ __forceinline__ bool sniff_is64(const void* edges) {
    const unsigned* up = (const unsigned*)edges;
    bool is64 = true;
#pragma unroll
    for (int k = 0; k < 16; k++) is64 = is64 && (up[2 * k + 1] == 0u);
    return is64;
}

// ---------- K0: 8-way counting scatter of edges into per-shard (src,dst) buckets ----
// R5 evidence: k1 was BW-bound (dur tracks bytes at ~1.2TB/s) and the removable bytes
// were (a) each XCD streaming the FULL 12.8MB edge array through its 4MB L2 (8x
// rescan, L3-absorbed in FETCH but thrashing dirty slot lines into WRITE) and (b)
// scattered 4B commits. Fix: ONE pass here builds contiguous per-shard buffers of
// int2(src,dst) with sequential writes; k1's cs role then reads only its own 0.8MB
// bucket. LDS histogram + per-thread prefix -> block-contiguous positions; one
// device atomic per bucket per block (8 x 196 total).
__global__ __launch_bounds__(256) void k_bucket(
        const void* __restrict__ edges, int E, int S,
        int2* __restrict__ bucket, int bcap, int* __restrict__ bucket_cnt) {
    __shared__ unsigned short hist[256][NSHARD];   // per-thread per-bucket counts
    __shared__ int base_sh[NSHARD];
    int t = threadIdx.x;
    int base = blockIdx.x * CHUNK_EDGES + t * 16;
    bool is64 = sniff_is64(edges);
    int sv[16], dv[16];
    int nv = E - base;
    if (nv > 16) nv = 16;
    if (nv < 0) nv = 0;
    if (nv == 16) {
        if (is64) {
            const ll2* ps = (const ll2*)((const long long*)edges + base);
            const ll2* pd = (const ll2*)((const long long*)edges + (size_t)E + base);
#pragma unroll
            for (int i = 0; i < 8; i++) {
                ll2 v = __builtin_nontemporal_load(ps + i);
                sv[2 * i] = (int)v.x; sv[2 * i + 1] = (int)v.y;
            }
#pragma unroll
            for (int i = 0; i < 8; i++) {
                ll2 w = __builtin_nontemporal_load(pd + i);
                dv[2 * i] = (int)w.x; dv[2 * i + 1] = (int)w.y;
            }
        } else {
            const i4v* ps = (const i4v*)((const int*)edges + base);
            const i4v* pd = (const i4v*)((const int*)edges + E + base);
#pragma unroll
            for (int i = 0; i < 4; i++) {
                i4v v = __builtin_nontemporal_load(ps + i);
                sv[4 * i] = v.x; sv[4 * i + 1] = v.y;
                sv[4 * i + 2] = v.z; sv[4 * i + 3] = v.w;
            }
#pragma unroll
            for (int i = 0; i < 4; i++) {
                i4v w = __builtin_nontemporal_load(pd + i);
                dv[4 * i] = w.x; dv[4 * i + 1] = w.y;
                dv[4 * i + 2] = w.z; dv[4 * i + 3] = w.w;
            }
        }
    } else {
        for (int i = 0; i < 16; i++) {
            if (i < nv) {
                if (is64) {
                    sv[i] = (int)((const long long*)edges)[base + i];
                    dv[i] = (int)((const long long*)edges)[(size_t)E + base + i];
                } else {
                    sv[i] = ((const int*)edges)[base + i];
                    dv[i] = ((const int*)edges)[E + base + i];
                }
            } else { sv[i] = 0; dv[i] = 0; }
        }
    }
    // bucket ids + per-thread histogram (all compile-time register indexing:
    // runtime-indexed reg arrays spill to scratch -> use unrolled compare chains)
    int bv[16];
    int tcnt[NSHARD];
#pragma unroll
    for (int b = 0; b < NSHARD; b++) tcnt[b] = 0;
#pragma unroll
    for (int i = 0; i < 16; i++) {
        int b = (i < nv) ? (int)((unsigned)dv[i] / (unsigned)S) : -1;
        bv[i] = b;
#pragma unroll
        for (int bb = 0; bb < NSHARD; bb++) tcnt[bb] += (b == bb);
    }
#pragma unroll
    for (int b = 0; b < NSHARD; b++) hist[t][b] = (unsigned short)tcnt[b];
    __syncthreads();
    if (t < NSHARD) {   // serial exclusive scan over 256 threads (8 scanners)
        int run = 0;
        for (int i = 0; i < 256; i++) {
            int c = hist[i][t];
            hist[i][t] = (unsigned short)run;
            run += c;
        }
        base_sh[t] = atomicAdd(bucket_cnt + t * 16, run);   // device scope, 8/block
    }
    __syncthreads();
    int off[NSHARD];
#pragma unroll
    for (int b = 0; b < NSHARD; b++) off[b] = base_sh[b] + (int)hist[t][b];
#pragma unroll
    for (int i = 0; i < 16; i++) {
        if (i < nv) {
            int b = bv[i];
#pragma unroll
            for (int bb = 0; bb < NSHARD; bb++) {
                if (b == bb) {
                    bucket[(size_t)bb * bcap + off[bb]] = make_int2(sv[i], dv[i]);
                    off[bb]++;
                }
            }
        }
    }
}

// ---------- K1: every block = {drain own-XCD bucket (cs)} then {drain mm tile queue}
// Fully dynamic roles: cs work keyed off the REAL XCD (s_getreg HW_REG_XCC_ID) +
// per-XCD chunk queue -> correctness independent of blockIdx->XCD mapping; mm tiles
// off a global device-scope queue. cs reads its contiguous bucket (sequential,
// L2/L3-hot), commits with WORKGROUP-scope (L2-local) atomics; single-writer-XCD
// invariant holds by construction. x loads + h16 stores NON-TEMPORAL: zero reuse in
// k1, keeps L2 free for the shard's slot/count lines (written back once).
__global__ __launch_bounds__(256) void k_mm_cs(
        const float* __restrict__ x, const float* __restrict__ W,
        const float* __restrict__ att, unsigned short* __restrict__ h16,
        float* __restrict__ asrc, float* __restrict__ adst, int N,
        const int2* __restrict__ bucket, int bcap,
        const int* __restrict__ bucket_cnt, int* __restrict__ counts,
        int* __restrict__ slots, int* __restrict__ oflow_cnt,
        int2* __restrict__ oflow, int mmb,
        int* __restrict__ queues, int* __restrict__ mmq) {
    __shared__ float Ws[IN_CH * OUT_CH];   // 32 KB (mm phase)
    __shared__ int grab_sh;
    int t = threadIdx.x;

    // ---- cs phase: drain own-XCD bucket ----
    int xcd;
    asm volatile("s_getreg_b32 %0, hwreg(HW_REG_XCC_ID)" : "=s"(xcd));
    xcd &= 7;
    int cnt = bucket_cnt[xcd * 16];
    int nchunks = (cnt + CHUNK_EDGES - 1) / CHUNK_EDGES;
    const int2* mybkt = bucket + (size_t)xcd * bcap;
    for (;;) {
        if (t == 0)
            grab_sh = __hip_atomic_fetch_add(queues + xcd * 16, 1,
                                             __ATOMIC_RELAXED,
                                             __HIP_MEMORY_SCOPE_WORKGROUP);
        __syncthreads();
        int chunk = grab_sh;
        __syncthreads();
        if (chunk >= nchunks) break;
        int base = chunk * CHUNK_EDGES + t * 16;
        int nv = cnt - base;
        if (nv > 16) nv = 16;
        if (nv > 0) {
            int2 ev[16];
            if (nv == 16) {
                const i4v* p = (const i4v*)(mybkt + base);
#pragma unroll
                for (int i = 0; i < 8; i++) {
                    i4v q = p[i];
                    ev[2 * i] = make_int2(q.x, q.y);
                    ev[2 * i + 1] = make_int2(q.z, q.w);
                }
            } else {
                for (int i = 0; i < 16; i++)
                    if (i < nv) ev[i] = mybkt[base + i];
            }
            int rr[16];
#pragma unroll
            for (int i = 0; i < 16; i++)
                if (i < nv)
                    rr[i] = __hip_atomic_fetch_add(counts + ev[i].y, 1,
                                                   __ATOMIC_RELAXED,
                                                   __HIP_MEMORY_SCOPE_WORKGROUP);
#pragma unroll
            for (int i = 0; i < 16; i++) {
                if (i < nv) {
                    if (rr[i] < CAP) {
                        slots[((size_t)ev[i].y << 6) + rr[i]] = ev[i].x;
                    } else {
                        int p2 = atomicAdd(oflow_cnt, 1);   // rare: device scope
                        oflow[p2] = make_int2(ev[i].x, ev[i].y);
                    }
                }
            }
        }
    }

    // ---- mm phase: W in LDS once, then drain global tile queue ----
    for (int i = t * 4; i < IN_CH * OUT_CH; i += 256 * 4)
        *(float4*)&Ws[i] = *(const float4*)&W[i];
    int cg = t & 15, g = t >> 4;
    float4 att_d = *(const float4*)&att[cg * 4];        // dst half: att[0:64]
    float4 att_s = *(const float4*)&att[64 + cg * 4];   // src half: att[64:128]
    __syncthreads();

    for (;;) {
        if (t == 0) grab_sh = atomicAdd(mmq, 1);   // device scope, ~1 per tile
        __syncthreads();
        int id = grab_sh;
        __syncthreads();
        if (id >= mmb) return;

        int n0 = id * 64 + g * 4;
        int nn[4];
#pragma unroll
        for (int m = 0; m < 4; m++) nn[m] = min(n0 + m, N - 1);

        float4 acc[4];
#pragma unroll
        for (int m = 0; m < 4; m++) acc[m] = make_float4(0.f, 0.f, 0.f, 0.f);

#pragma unroll 2
        for (int k4 = 0; k4 < IN_CH / 4; k4++) {
            f4v xv[4];
#pragma unroll
            for (int m = 0; m < 4; m++)
                xv[m] = __builtin_nontemporal_load(
                    (const f4v*)&x[(size_t)nn[m] * IN_CH + k4 * 4]);
            float4 wv[4];
#pragma unroll
            for (int j = 0; j < 4; j++)
                wv[j] = *(const float4*)&Ws[(k4 * 4 + j) * OUT_CH + cg * 4];
#pragma unroll
            for (int m = 0; m < 4; m++) {
                acc[m].x = fmaf(xv[m].x, wv[0].x, acc[m].x);
                acc[m].y = fmaf(xv[m].x, wv[0].y, acc[m].y);
                acc[m].z = fmaf(xv[m].x, wv[0].z, acc[m].z);
                acc[m].w = fmaf(xv[m].x, wv[0].w, acc[m].w);
                acc[m].x = fmaf(xv[m].y, wv[1].x, acc[m].x);
                acc[m].y = fmaf(xv[m].y, wv[1].y, acc[m].y);
                acc[m].z = fmaf(xv[m].y, wv[1].z, acc[m].z);
                acc[m].w = fmaf(xv[m].y, wv[1].w, acc[m].w);
                acc[m].x = fmaf(xv[m].z, wv[2].x, acc[m].x);
                acc[m].y = fmaf(xv[m].z, wv[2].y, acc[m].y);
                acc[m].z = fmaf(xv[m].z, wv[2].z, acc[m].z);
                acc[m].w = fmaf(xv[m].z, wv[2].w, acc[m].w);
                acc[m].x = fmaf(xv[m].w, wv[3].x, acc[m].x);
                acc[m].y = fmaf(xv[m].w, wv[3].y, acc[m].y);
                acc[m].z = fmaf(xv[m].w, wv[3].z, acc[m].z);
                acc[m].w = fmaf(xv[m].w, wv[3].w, acc[m].w);
            }
        }

#pragma unroll
        for (int m = 0; m < 4; m++) {
            int node = n0 + m;
            if (node < N) {
                us4v hv;
                hv.x = f2bf(acc[m].x);
                hv.y = f2bf(acc[m].y);
                hv.z = f2bf(acc[m].z);
                hv.w = f2bf(acc[m].w);
                __builtin_nontemporal_store(
                    hv, (us4v*)&h16[(size_t)node * OUT_CH + cg * 4]);
            }
            float pd = acc[m].x * att_d.x + acc[m].y * att_d.y +
                       acc[m].z * att_d.z + acc[m].w * att_d.w;
            float ps = acc[m].x * att_s.x + acc[m].y * att_s.y +
                       acc[m].z * att_s.z + acc[m].w * att_s.w;
#pragma unroll
            for (int msk = 1; msk < 16; msk <<= 1) {
                pd += __shfl_xor(pd, msk, 64);
                ps += __shfl_xor(ps, msk, 64);
            }
            if (cg == 0 && node < N) { adst[node] = pd; asrc[node] = ps; }
        }
    }
}

// ---------- K2: per-node slot-gather softmax-aggregate + bias + L2 normalize ----------
// 1 wave/node, 2 channels/lane (ushort2), half-waves cover 2 src rows per load.
__global__ __launch_bounds__(256) void k_agg(const unsigned short* __restrict__ h16,
                                             const int* __restrict__ slots,
                                             const int* __restrict__ counts,
                                             const int* __restrict__ oflow_cnt,
                                             const int2* __restrict__ oflow,
                                             const float* __restrict__ asrc,
                                             const float* __restrict__ adst,
                                             const float* __restrict__ bias,
                                             float* __restrict__ out, int N) {
    __shared__ float2 stage[4][64];   // wave-private
    int lane = threadIdx.x & 63;
    int wid = threadIdx.x >> 6;
    int node = blockIdx.x * 4 + wid;
    if (node >= N) return;
    int half = lane >> 5;
    int ch2 = (lane & 31) * 2;

    float aD = adst[node];
    // analytic self loop (h row counted in half 0 only)
    float a = aD + asrc[node];
    a = a > 0.f ? a : NEG_SLOPE * a;
    float w_self = __expf(a);
    unsigned hv = *(const unsigned*)&h16[(size_t)node * OUT_CH + ch2];
    float wse = half ? 0.f : w_self;
    float accx = wse * __uint_as_float(hv << 16);
    float accy = wse * __uint_as_float(hv & 0xFFFF0000u);

    int c = counts[node];           // true degree (may exceed CAP)
    int cs = min(c, CAP);
    int sv = 0;
    float wv = 0.f;
    if (lane < cs) {
        sv = slots[((size_t)node << 6) + lane];   // coalesced 256B
        float av = aD + asrc[sv];                 // parallel gather (L2-hot)
        av = av > 0.f ? av : NEG_SLOPE * av;
        wv = __expf(av);                          // once per edge
    }
    float esum_lane = wv;
    stage[wid][lane] = make_float2(__int_as_float(sv), wv);

    for (int j = 0; j < cs; j += 16) {
#pragma unroll
        for (int k = 0; k < 8; k++) {
            float2 p = stage[wid][j + 2 * k + half];   // 2-addr broadcast, free
            int s = __float_as_int(p.x);
            unsigned v = *(const unsigned*)&h16[((size_t)s << 6) + ch2];
            accx = fmaf(p.y, __uint_as_float(v << 16), accx);
            accy = fmaf(p.y, __uint_as_float(v & 0xFFFF0000u), accy);
        }
    }
    // combine half-waves (even rows in lanes 0-31, odd rows in 32-63)
    accx += __shfl_xor(accx, 32, 64);
    accy += __shfl_xor(accy, 32, 64);
#pragma unroll
    for (int m = 32; m >= 1; m >>= 1) esum_lane += __shfl_xor(esum_lane, m, 64);
    float esum = esum_lane + w_self;

    // cold overflow path (oc == 0 for this input; correct if not)
    int oc = *oflow_cnt;
    if (oc > 0) {
        for (int i = 0; i < oc; i++) {
            int2 e = oflow[i];
            if (e.y == node) {
                float av = aD + asrc[e.x];
                av = av > 0.f ? av : NEG_SLOPE * av;
                float w = __expf(av);
                esum += w;
                unsigned v = *(const unsigned*)&h16[((size_t)e.x << 6) + ch2];
                accx = fmaf(w, __uint_as_float(v << 16), accx);
                accy = fmaf(w, __uint_as_float(v & 0xFFFF0000u), accy);
            }
        }
    }

    float inv = 1.f / (esum + 1e-16f);
    float2 bv = *(const float2*)&bias[ch2];
    float vx = accx * inv + bv.x;
    float vy = accy * inv + bv.y;
    float ss = vx * vx + vy * vy;
#pragma unroll
    for (int m = 16; m >= 1; m >>= 1) ss += __shfl_xor(ss, m, 64);   // within half
    float rinv = 1.f / fmaxf(sqrtf(ss), 1e-12f);
    if (!half)
        *(float2*)&out[(size_t)node * OUT_CH + ch2] = make_float2(vx * rinv, vy * rinv);
}

extern "C" void kernel_launch(void* const* d_in, const int* in_sizes, int n_in,
                              void* d_out, int out_size, void* d_ws, size_t ws_size,
                              hipStream_t stream) {
    const float* x    = (const float*)d_in[0];
    const void*  edges = d_in[1];
    const float* W    = (const float*)d_in[2];
    const float* att  = (const float*)d_in[3];
    const float* bias = (const float*)d_in[4];
    float* out = (float*)d_out;

    const int N = in_sizes[0] / IN_CH;
    const int E = in_sizes[1] / 2;
    const int S = (N + NSHARD - 1) / NSHARD;             // shard width (b = d/S)
    const int MMB = (N + 63) / 64;                       // 782 mm tiles
    const int BKB = (E + CHUNK_EDGES - 1) / CHUNK_EDGES; // 196 bucket blocks
    const int bcap = E / NSHARD + 16384;                 // per-shard capacity
    const int grid1 = MMB + 256;                         // k1 blocks (dynamic roles)

    char* ws = (char*)d_ws;
    size_t off = 0;
    auto alloc = [&](size_t bytes) -> void* {
        void* p = ws + off;
        off += bytes;
        off = (off + 255) & ~(size_t)255;
        return p;
    };
    // counts[N] | oflow_cnt @N | queues @N+64 | bucket_cnt @N+192 | mmq @N+320
    int*            counts   = (int*)alloc((size_t)(N + 384) * 4);
    int*            slots    = (int*)alloc((size_t)N * CAP * 4);     // 12.8 MB
    int2*           oflow    = (int2*)alloc((size_t)65536 * 8);      // stat-impossible
    unsigned short* h16      = (unsigned short*)alloc((size_t)N * OUT_CH * 2);
    float*          asrc     = (float*)alloc((size_t)N * 4);
    float*          adst     = (float*)alloc((size_t)N * 4);
    int2*           bucket   = (int2*)alloc((size_t)NSHARD * bcap * 8);  // ~7.4 MB
    int*            oflow_cnt  = counts + N;
    int*            queues     = counts + N + 64;
    int*            bucket_cnt = counts + N + 192;
    int*            mmq        = counts + N + 320;

    hipMemsetAsync(counts, 0, (size_t)(N + 384) * 4, stream);
    k_bucket<<<BKB, 256, 0, stream>>>(edges, E, S, bucket, bcap, bucket_cnt);
    k_mm_cs<<<grid1, 256, 0, stream>>>(x, W, att, h16, asrc, adst, N,
                                       bucket, bcap, bucket_cnt, counts,
                                       slots, oflow_cnt, oflow, MMB, queues, mmq);
    k_agg<<<(N + 3) / 4, 256, 0, stream>>>(h16, slots, counts, oflow_cnt, oflow,
                                           asrc, adst, bias, out, N);
}

// Round 7
// 139.798 us; speedup vs baseline: 1.3147x; 1.3147x over previous
//
#include <hip/hip_runtime.h>
#include <math.h>

#define IN_CH 128
#define OUT_CH 64
#define NEG_SLOPE 0.2f
#define CAP 64           // slots per node; mean degree 16, P(deg>64) ~ 1e-16
#define BSHIFT 8         // 256 nodes per dst-bucket -> bucket id = dst >> 8
#define BS 256           // bucket width (nodes); counts writes stay line-aligned
#define CHUNK_EDGES 4096 // edges per k_bucket block (256 thr x 16)

typedef long long ll2 __attribute__((ext_vector_type(2)));
typedef int i4v __attribute__((ext_vector_type(4)));

// ---------- bf16 helpers ----------
__device__ __forceinline__ unsigned short f2bf(float f) {
    unsigned u = __float_as_uint(f);
    unsigned r = (u + 0x7FFFu + ((u >> 16) & 1u)) >> 16;   // round-nearest-even
    return (unsigned short)r;
}

// ---------- edge dtype sniff: int64 little-endian => odd int32 words are 0 ----------
__device__ __forceinline__ bool sniff_is64(const void* edges) {
    const unsigned* up = (const unsigned*)edges;
    bool is64 = true;
#pragma unroll
    for (int k = 0; k < 16; k++) is64 = is64 && (up[2 * k + 1] == 0u);
    return is64;
}

// ---------- K0: scatter edges into per-256-node-range buckets ----------
// R4-R6 evidence: the ~25MB WRITE excess and the ~55us k1 floor were the 800K
// per-edge GLOBAL atomics (each a memory-side 32B transaction + fabric round trip,
// regardless of scope). This pass sets up their complete elimination: exclusive
// per-bucket ownership in k1 means counting can be LDS-local there.
// Positions here: LDS cursor per bucket gives each edge a stable slot within the
// block's allocation; ONE device atomic per (block,bucket) reserves the global run
// (~38K atomics total vs 800K). Bucket writes are contiguous ~170B runs per
// (block,bucket). nbkt = ceil(N/256) must be <= 256 (true for N=50000: 196).
__global__ __launch_bounds__(256) void k_bucket(
        const void* __restrict__ edges, int E, int nbkt,
        int2* __restrict__ bucket, int bcap, int* __restrict__ bucket_cnt) {
    __shared__ int lcur[256];
    __shared__ int lbase[256];
    int t = threadIdx.x;
    lcur[t] = 0;
    __syncthreads();

    int base = blockIdx.x * CHUNK_EDGES + t * 16;
    bool is64 = sniff_is64(edges);
    int sv[16], dv[16], rr[16];
    int nv = E - base;
    if (nv > 16) nv = 16;
    if (nv < 0) nv = 0;
    if (nv == 16) {
        if (is64) {
            const ll2* ps = (const ll2*)((const long long*)edges + base);
            const ll2* pd = (const ll2*)((const long long*)edges + (size_t)E + base);
#pragma unroll
            for (int i = 0; i < 8; i++) {
                ll2 v = __builtin_nontemporal_load(ps + i);
                sv[2 * i] = (int)v.x; sv[2 * i + 1] = (int)v.y;
            }
#pragma unroll
            for (int i = 0; i < 8; i++) {
                ll2 w = __builtin_nontemporal_load(pd + i);
                dv[2 * i] = (int)w.x; dv[2 * i + 1] = (int)w.y;
            }
        } else {
            const i4v* ps = (const i4v*)((const int*)edges + base);
            const i4v* pd = (const i4v*)((const int*)edges + E + base);
#pragma unroll
            for (int i = 0; i < 4; i++) {
                i4v v = __builtin_nontemporal_load(ps + i);
                sv[4 * i] = v.x; sv[4 * i + 1] = v.y;
                sv[4 * i + 2] = v.z; sv[4 * i + 3] = v.w;
            }
#pragma unroll
            for (int i = 0; i < 4; i++) {
                i4v w = __builtin_nontemporal_load(pd + i);
                dv[4 * i] = w.x; dv[4 * i + 1] = w.y;
                dv[4 * i + 2] = w.z; dv[4 * i + 3] = w.w;
            }
        }
    } else {
        for (int i = 0; i < 16; i++) {
            if (i < nv) {
                if (is64) {
                    sv[i] = (int)((const long long*)edges)[base + i];
                    dv[i] = (int)((const long long*)edges)[(size_t)E + base + i];
                } else {
                    sv[i] = ((const int*)edges)[base + i];
                    dv[i] = ((const int*)edges)[E + base + i];
                }
            } else { sv[i] = 0; dv[i] = 0; }
        }
    }
    // phase 1: LDS-cursor positions (order within bucket is irrelevant downstream)
#pragma unroll
    for (int i = 0; i < 16; i++)
        if (i < nv) rr[i] = atomicAdd(&lcur[(unsigned)dv[i] >> BSHIFT], 1);
    __syncthreads();
    // phase 2: one device atomic per non-empty (block,bucket)
    if (t < nbkt && lcur[t] > 0) lbase[t] = atomicAdd(bucket_cnt + t, lcur[t]);
    __syncthreads();
    // phase 3: place edges (contiguous run per bucket)
#pragma unroll
    for (int i = 0; i < 16; i++) {
        if (i < nv) {
            int b = (unsigned)dv[i] >> BSHIFT;
            bucket[(size_t)b * bcap + lbase[b] + rr[i]] = make_int2(sv[i], dv[i]);
        }
    }
}

// ---------- K1: mm blocks + exclusive-bucket cs blocks (ZERO global atomics) -------
// cs block owns bucket id exclusively: LDS count array gives slot index r per edge
// (LDS atomic, no HBM traffic); slots written once with plain stores; counts[range]
// written once, coalesced, line-aligned (BS=256 -> 1KB). No scope tricks, no XCD
// identity needed -- exclusivity is structural. x / h16 / slots are PLAIN cacheable
// accesses now: h16 must be L3-resident for k_agg's 800K row-gathers (R6's nt h16
// store pushed those to HBM).
__global__ __launch_bounds__(256) void k_mm_cs(
        const float* __restrict__ x, const float* __restrict__ W,
        const float* __restrict__ att, unsigned short* __restrict__ h16,
        float* __restrict__ asrc, float* __restrict__ adst, int N,
        const int2* __restrict__ bucket, int bcap,
        const int* __restrict__ bucket_cnt, int* __restrict__ counts,
        int* __restrict__ slots, int* __restrict__ oflow_cnt,
        int2* __restrict__ oflow, int mmb, int csb) {
    __shared__ float Ws[IN_CH * OUT_CH];   // 32 KB (mm); cs aliases first 1KB
    int t = threadIdx.x;
    int bid = blockIdx.x;
    int total = mmb + csb;
    // Bresenham spread: cs blocks (minority, 1-in-5) evenly through the grid
    int cbefore = (int)(((long long)bid * csb) / total);
    int cafter  = (int)(((long long)(bid + 1) * csb) / total);
    bool iscs = (cafter != cbefore);
    int id = iscs ? cbefore : (bid - cbefore);

    if (iscs) {
        int* lcnt = (int*)Ws;
        int lo = id << BSHIFT;
        lcnt[t] = 0;
        __syncthreads();
        int cnt = bucket_cnt[id];
        const int2* mybkt = bucket + (size_t)id * bcap;
        for (int idx = t; idx < cnt; idx += 256) {
            int2 e = mybkt[idx];                       // coalesced 2KB per sweep
            int r = atomicAdd(&lcnt[e.y - lo], 1);     // LDS: ~free vs 700cy fabric
            if (r < CAP) {
                slots[((size_t)e.y << 6) + r] = e.x;   // exclusive, written once
            } else {
                int p2 = atomicAdd(oflow_cnt, 1);      // statistically never
                oflow[p2] = e;
            }
        }
        __syncthreads();
        int node = lo + t;
        if (node < N) counts[node] = lcnt[t];          // coalesced 1KB, line-aligned
        return;
    }

    // ----- mm role: 64 nodes/block, W staged in LDS -----
    for (int i = t * 4; i < IN_CH * OUT_CH; i += 256 * 4)
        *(float4*)&Ws[i] = *(const float4*)&W[i];
    int cg = t & 15, g = t >> 4;
    float4 att_d = *(const float4*)&att[cg * 4];        // dst half: att[0:64]
    float4 att_s = *(const float4*)&att[64 + cg * 4];   // src half: att[64:128]
    __syncthreads();

    int n0 = id * 64 + g * 4;
    int nn[4];
#pragma unroll
    for (int m = 0; m < 4; m++) nn[m] = min(n0 + m, N - 1);

    float4 acc[4];
#pragma unroll
    for (int m = 0; m < 4; m++) acc[m] = make_float4(0.f, 0.f, 0.f, 0.f);

#pragma unroll 2
    for (int k4 = 0; k4 < IN_CH / 4; k4++) {
        float4 xv[4];
#pragma unroll
        for (int m = 0; m < 4; m++)
            xv[m] = *(const float4*)&x[(size_t)nn[m] * IN_CH + k4 * 4];
        float4 wv[4];
#pragma unroll
        for (int j = 0; j < 4; j++)
            wv[j] = *(const float4*)&Ws[(k4 * 4 + j) * OUT_CH + cg * 4];
#pragma unroll
        for (int m = 0; m < 4; m++) {
            acc[m].x = fmaf(xv[m].x, wv[0].x, acc[m].x);
            acc[m].y = fmaf(xv[m].x, wv[0].y, acc[m].y);
            acc[m].z = fmaf(xv[m].x, wv[0].z, acc[m].z);
            acc[m].w = fmaf(xv[m].x, wv[0].w, acc[m].w);
            acc[m].x = fmaf(xv[m].y, wv[1].x, acc[m].x);
            acc[m].y = fmaf(xv[m].y, wv[1].y, acc[m].y);
            acc[m].z = fmaf(xv[m].y, wv[1].z, acc[m].z);
            acc[m].w = fmaf(xv[m].y, wv[1].w, acc[m].w);
            acc[m].x = fmaf(xv[m].z, wv[2].x, acc[m].x);
            acc[m].y = fmaf(xv[m].z, wv[2].y, acc[m].y);
            acc[m].z = fmaf(xv[m].z, wv[2].z, acc[m].z);
            acc[m].w = fmaf(xv[m].z, wv[2].w, acc[m].w);
            acc[m].x = fmaf(xv[m].w, wv[3].x, acc[m].x);
            acc[m].y = fmaf(xv[m].w, wv[3].y, acc[m].y);
            acc[m].z = fmaf(xv[m].w, wv[3].z, acc[m].z);
            acc[m].w = fmaf(xv[m].w, wv[3].w, acc[m].w);
        }
    }

#pragma unroll
    for (int m = 0; m < 4; m++) {
        int node = n0 + m;
        if (node < N) {
            ushort4 hv;
            hv.x = f2bf(acc[m].x);
            hv.y = f2bf(acc[m].y);
            hv.z = f2bf(acc[m].z);
            hv.w = f2bf(acc[m].w);
            *(ushort4*)&h16[(size_t)node * OUT_CH + cg * 4] = hv;
        }
        float pd = acc[m].x * att_d.x + acc[m].y * att_d.y +
                   acc[m].z * att_d.z + acc[m].w * att_d.w;
        float ps = acc[m].x * att_s.x + acc[m].y * att_s.y +
                   acc[m].z * att_s.z + acc[m].w * att_s.w;
#pragma unroll
        for (int msk = 1; msk < 16; msk <<= 1) {
            pd += __shfl_xor(pd, msk, 64);
            ps += __shfl_xor(ps, msk, 64);
        }
        if (cg == 0 && node < N) { adst[node] = pd; asrc[node] = ps; }
    }
}

// ---------- K2: per-node slot-gather softmax-aggregate + bias + L2 normalize ----------
// 1 wave/node, 2 channels/lane (ushort2), half-waves cover 2 src rows per load.
__global__ __launch_bounds__(256) void k_agg(const unsigned short* __restrict__ h16,
                                             const int* __restrict__ slots,
                                             const int* __restrict__ counts,
                                             const int* __restrict__ oflow_cnt,
                                             const int2* __restrict__ oflow,
                                             const float* __restrict__ asrc,
                                             const float* __restrict__ adst,
                                             const float* __restrict__ bias,
                                             float* __restrict__ out, int N) {
    __shared__ float2 stage[4][64];   // wave-private
    int lane = threadIdx.x & 63;
    int wid = threadIdx.x >> 6;
    int node = blockIdx.x * 4 + wid;
    if (node >= N) return;
    int half = lane >> 5;
    int ch2 = (lane & 31) * 2;

    float aD = adst[node];
    // analytic self loop (h row counted in half 0 only)
    float a = aD + asrc[node];
    a = a > 0.f ? a : NEG_SLOPE * a;
    float w_self = __expf(a);
    unsigned hv = *(const unsigned*)&h16[(size_t)node * OUT_CH + ch2];
    float wse = half ? 0.f : w_self;
    float accx = wse * __uint_as_float(hv << 16);
    float accy = wse * __uint_as_float(hv & 0xFFFF0000u);

    int c = counts[node];           // true degree (may exceed CAP)
    int cs = min(c, CAP);
    int sv = 0;
    float wv = 0.f;
    if (lane < cs) {
        sv = slots[((size_t)node << 6) + lane];   // coalesced 256B
        float av = aD + asrc[sv];                 // parallel gather (L2-hot)
        av = av > 0.f ? av : NEG_SLOPE * av;
        wv = __expf(av);                          // once per edge
    }
    float esum_lane = wv;
    stage[wid][lane] = make_float2(__int_as_float(sv), wv);

    for (int j = 0; j < cs; j += 16) {
#pragma unroll
        for (int k = 0; k < 8; k++) {
            float2 p = stage[wid][j + 2 * k + half];   // 2-addr broadcast, free
            int s = __float_as_int(p.x);
            unsigned v = *(const unsigned*)&h16[((size_t)s << 6) + ch2];
            accx = fmaf(p.y, __uint_as_float(v << 16), accx);
            accy = fmaf(p.y, __uint_as_float(v & 0xFFFF0000u), accy);
        }
    }
    // combine half-waves (even rows in lanes 0-31, odd rows in 32-63)
    accx += __shfl_xor(accx, 32, 64);
    accy += __shfl_xor(accy, 32, 64);
#pragma unroll
    for (int m = 32; m >= 1; m >>= 1) esum_lane += __shfl_xor(esum_lane, m, 64);
    float esum = esum_lane + w_self;

    // cold overflow path (oc == 0 for this input; correct if not)
    int oc = *oflow_cnt;
    if (oc > 0) {
        for (int i = 0; i < oc; i++) {
            int2 e = oflow[i];
            if (e.y == node) {
                float av = aD + asrc[e.x];
                av = av > 0.f ? av : NEG_SLOPE * av;
                float w = __expf(av);
                esum += w;
                unsigned v = *(const unsigned*)&h16[((size_t)e.x << 6) + ch2];
                accx = fmaf(w, __uint_as_float(v << 16), accx);
                accy = fmaf(w, __uint_as_float(v & 0xFFFF0000u), accy);
            }
        }
    }

    float inv = 1.f / (esum + 1e-16f);
    float2 bv = *(const float2*)&bias[ch2];
    float vx = accx * inv + bv.x;
    float vy = accy * inv + bv.y;
    float ss = vx * vx + vy * vy;
#pragma unroll
    for (int m = 16; m >= 1; m >>= 1) ss += __shfl_xor(ss, m, 64);   // within half
    float rinv = 1.f / fmaxf(sqrtf(ss), 1e-12f);
    if (!half)
        *(float2*)&out[(size_t)node * OUT_CH + ch2] = make_float2(vx * rinv, vy * rinv);
}

extern "C" void kernel_launch(void* const* d_in, const int* in_sizes, int n_in,
                              void* d_out, int out_size, void* d_ws, size_t ws_size,
                              hipStream_t stream) {
    const float* x    = (const float*)d_in[0];
    const void*  edges = d_in[1];
    const float* W    = (const float*)d_in[2];
    const float* att  = (const float*)d_in[3];
    const float* bias = (const float*)d_in[4];
    float* out = (float*)d_out;

    const int N = in_sizes[0] / IN_CH;
    const int E = in_sizes[1] / 2;
    const int NBKT = (N + BS - 1) / BS;                  // 196 buckets (<=256)
    const int MMB = (N + 63) / 64;                       // 782 mm blocks
    const int BKB = (E + CHUNK_EDGES - 1) / CHUNK_EDGES; // 196 bucket blocks
    // per-bucket capacity: mean E/NBKT=4082, sigma~64 -> 6144 is >30 sigma
    const int bcap = E / NBKT + 2048;

    char* ws = (char*)d_ws;
    size_t off = 0;
    auto alloc = [&](size_t bytes) -> void* {
        void* p = ws + off;
        off += bytes;
        off = (off + 255) & ~(size_t)255;
        return p;
    };
    // small control block (memset target): bucket_cnt[256] | oflow_cnt @256
    int*            ctrl     = (int*)alloc(320 * 4);
    int*            counts   = (int*)alloc((size_t)N * 4);         // fully written by cs
    int*            slots    = (int*)alloc((size_t)N * CAP * 4);   // 12.8 MB
    int2*           oflow    = (int2*)alloc((size_t)65536 * 8);    // stat-impossible
    unsigned short* h16      = (unsigned short*)alloc((size_t)N * OUT_CH * 2);
    float*          asrc     = (float*)alloc((size_t)N * 4);
    float*          adst     = (float*)alloc((size_t)N * 4);
    int2*           bucket   = (int2*)alloc((size_t)NBKT * bcap * 8);  // ~9.6 MB
    int*            bucket_cnt = ctrl;
    int*            oflow_cnt  = ctrl + 256;

    hipMemsetAsync(ctrl, 0, 320 * 4, stream);
    k_bucket<<<BKB, 256, 0, stream>>>(edges, E, NBKT, bucket, bcap, bucket_cnt);
    k_mm_cs<<<MMB + NBKT, 256, 0, stream>>>(x, W, att, h16, asrc, adst, N,
                                            bucket, bcap, bucket_cnt, counts,
                                            slots, oflow_cnt, oflow, MMB, NBKT);
    k_agg<<<(N + 3) / 4, 256, 0, stream>>>(h16, slots, counts, oflow_cnt, oflow,
                                           asrc, adst, bias, out, N);
}

// Round 8
// 135.644 us; speedup vs baseline: 1.3550x; 1.0306x over previous
//
#include <hip/hip_runtime.h>
#include <math.h>

#define IN_CH 128
#define OUT_CH 64
#define NEG_SLOPE 0.2f
#define CAP 64           // slots per node; mean degree 16, P(deg>64) ~ 1e-16
#define BSHIFT 8         // 256 nodes per dst-bucket -> bucket id = dst >> 8
#define BS 256           // bucket width (nodes); counts writes stay line-aligned
#define CHUNK_EDGES 4096 // edges per k_bucket block (256 thr x 16)

typedef long long ll2 __attribute__((ext_vector_type(2)));
typedef int i4v __attribute__((ext_vector_type(4)));

// ---------- bf16 helpers ----------
__device__ __forceinline__ unsigned short f2bf(float f) {
    unsigned u = __float_as_uint(f);
    unsigned r = (u + 0x7FFFu + ((u >> 16) & 1u)) >> 16;   // round-nearest-even
    return (unsigned short)r;
}

// ---------- direct global->LDS 16B copy (lane i writes ldsbase + i*16) ----------
__device__ __forceinline__ void gload_lds16(const void* g, void* l) {
    __builtin_amdgcn_global_load_lds(
        (const __attribute__((address_space(1))) void*)g,
        (__attribute__((address_space(3))) void*)l, 16, 0, 0);
}

// ---------- edge dtype sniff: int64 little-endian => odd int32 words are 0 ----------
__device__ __forceinline__ bool sniff_is64(const void* edges) {
    const unsigned* up = (const unsigned*)edges;
    bool is64 = true;
#pragma unroll
    for (int k = 0; k < 16; k++) is64 = is64 && (up[2 * k + 1] == 0u);
    return is64;
}

// ---------- K0: scatter edges into per-256-node-range buckets ----------
// (unchanged from R7 -- sets up exclusive per-bucket ownership so k1's cs role
// counts with LDS atomics only; ~38K device atomics total vs 800K per-edge.)
__global__ __launch_bounds__(256) void k_bucket(
        const void* __restrict__ edges, int E, int nbkt,
        int2* __restrict__ bucket, int bcap, int* __restrict__ bucket_cnt) {
    __shared__ int lcur[256];
    __shared__ int lbase[256];
    int t = threadIdx.x;
    lcur[t] = 0;
    __syncthreads();

    int base = blockIdx.x * CHUNK_EDGES + t * 16;
    bool is64 = sniff_is64(edges);
    int sv[16], dv[16], rr[16];
    int nv = E - base;
    if (nv > 16) nv = 16;
    if (nv < 0) nv = 0;
    if (nv == 16) {
        if (is64) {
            const ll2* ps = (const ll2*)((const long long*)edges + base);
            const ll2* pd = (const ll2*)((const long long*)edges + (size_t)E + base);
#pragma unroll
            for (int i = 0; i < 8; i++) {
                ll2 v = __builtin_nontemporal_load(ps + i);
                sv[2 * i] = (int)v.x; sv[2 * i + 1] = (int)v.y;
            }
#pragma unroll
            for (int i = 0; i < 8; i++) {
                ll2 w = __builtin_nontemporal_load(pd + i);
                dv[2 * i] = (int)w.x; dv[2 * i + 1] = (int)w.y;
            }
        } else {
            const i4v* ps = (const i4v*)((const int*)edges + base);
            const i4v* pd = (const i4v*)((const int*)edges + E + base);
#pragma unroll
            for (int i = 0; i < 4; i++) {
                i4v v = __builtin_nontemporal_load(ps + i);
                sv[4 * i] = v.x; sv[4 * i + 1] = v.y;
                sv[4 * i + 2] = v.z; sv[4 * i + 3] = v.w;
            }
#pragma unroll
            for (int i = 0; i < 4; i++) {
                i4v w = __builtin_nontemporal_load(pd + i);
                dv[4 * i] = w.x; dv[4 * i + 1] = w.y;
                dv[4 * i + 2] = w.z; dv[4 * i + 3] = w.w;
            }
        }
    } else {
        for (int i = 0; i < 16; i++) {
            if (i < nv) {
                if (is64) {
                    sv[i] = (int)((const long long*)edges)[base + i];
                    dv[i] = (int)((const long long*)edges)[(size_t)E + base + i];
                } else {
                    sv[i] = ((const int*)edges)[base + i];
                    dv[i] = ((const int*)edges)[E + base + i];
                }
            } else { sv[i] = 0; dv[i] = 0; }
        }
    }
    // phase 1: LDS-cursor positions (order within bucket is irrelevant downstream)
#pragma unroll
    for (int i = 0; i < 16; i++)
        if (i < nv) rr[i] = atomicAdd(&lcur[(unsigned)dv[i] >> BSHIFT], 1);
    __syncthreads();
    // phase 2: one device atomic per non-empty (block,bucket)
    if (t < nbkt && lcur[t] > 0) lbase[t] = atomicAdd(bucket_cnt + t, lcur[t]);
    __syncthreads();
    // phase 3: place edges (contiguous run per bucket)
#pragma unroll
    for (int i = 0; i < 16; i++) {
        if (i < nv) {
            int b = (unsigned)dv[i] >> BSHIFT;
            bucket[(size_t)b * bcap + lbase[b] + rr[i]] = make_int2(sv[i], dv[i]);
        }
    }
}

// ---------- K1: mm blocks (LDS-staged x tile) + exclusive-bucket cs blocks ----------
// R7 back-solve: mm role was ~25-30us for 25.6MB compulsory x traffic (~1TB/s
// effective) because x loads were 16-way REPLICATED (64B unique data per VMEM
// instruction) at ~2.4 blocks/CU -- latency-starved, not BW-limited. Fix: stage the
// 64x128 x tile direct-to-LDS with global_load_lds width=16 (1KB unique coalesced
// data per wave-instruction, no VGPR round trip), then read Xs via LDS broadcast.
// Staging rows clamp at N-1 (tail block stays in bounds). cs role unchanged (zero
// global atomics; LDS count cursor; counts written once, coalesced).
__global__ __launch_bounds__(256) void k_mm_cs(
        const float* __restrict__ x, const float* __restrict__ W,
        const float* __restrict__ att, unsigned short* __restrict__ h16,
        float* __restrict__ asrc, float* __restrict__ adst, int N,
        const int2* __restrict__ bucket, int bcap,
        const int* __restrict__ bucket_cnt, int* __restrict__ counts,
        int* __restrict__ slots, int* __restrict__ oflow_cnt,
        int2* __restrict__ oflow, int mmb, int csb) {
    __shared__ float Ws[IN_CH * OUT_CH];   // 32 KB weights (mm); cs aliases 1KB
    __shared__ float Xs[64 * IN_CH];       // 32 KB x tile (mm only)
    int t = threadIdx.x;
    int bid = blockIdx.x;
    int total = mmb + csb;
    // Bresenham spread: cs blocks (minority, 1-in-5) evenly through the grid
    int cbefore = (int)(((long long)bid * csb) / total);
    int cafter  = (int)(((long long)(bid + 1) * csb) / total);
    bool iscs = (cafter != cbefore);
    int id = iscs ? cbefore : (bid - cbefore);

    if (iscs) {
        int* lcnt = (int*)Ws;
        int lo = id << BSHIFT;
        lcnt[t] = 0;
        __syncthreads();
        int cnt = bucket_cnt[id];
        const int2* mybkt = bucket + (size_t)id * bcap;
        for (int idx = t; idx < cnt; idx += 256) {
            int2 e = mybkt[idx];                       // coalesced 2KB per sweep
            int r = atomicAdd(&lcnt[e.y - lo], 1);     // LDS: ~free vs 700cy fabric
            if (r < CAP) {
                slots[((size_t)e.y << 6) + r] = e.x;   // exclusive, written once
            } else {
                int p2 = atomicAdd(oflow_cnt, 1);      // statistically never
                oflow[p2] = e;
            }
        }
        __syncthreads();
        int node = lo + t;
        if (node < N) counts[node] = lcnt[t];          // coalesced 1KB, line-aligned
        return;
    }

    // ----- mm role: 64 nodes/block; x tile + W staged in LDS -----
    {
        int wv_ = t >> 6;          // wave id 0..3
        int lane = t & 63;
        int col16 = (lane & 31) * 4;                   // 16B column chunk (floats)
#pragma unroll
        for (int i = 0; i < 8; i++) {
            int seg = wv_ * 8 + i;                     // 1KB segment = 2 rows
            int row = id * 64 + seg * 2 + (lane >> 5);
            row = min(row, N - 1);                     // tail clamp (dup row N-1)
            gload_lds16(&x[(size_t)row * IN_CH + col16], &Xs[seg * 256]);
        }
    }
    for (int i = t * 4; i < IN_CH * OUT_CH; i += 256 * 4)
        *(float4*)&Ws[i] = *(const float4*)&W[i];
    int cg = t & 15, g = t >> 4;
    float4 att_d = *(const float4*)&att[cg * 4];        // dst half: att[0:64]
    float4 att_s = *(const float4*)&att[64 + cg * 4];   // src half: att[64:128]
    __syncthreads();   // drains vmcnt (global_load_lds) + lgkmcnt (ds_write)

    int n0 = id * 64 + g * 4;

    float4 acc[4];
#pragma unroll
    for (int m = 0; m < 4; m++) acc[m] = make_float4(0.f, 0.f, 0.f, 0.f);

#pragma unroll 2
    for (int k4 = 0; k4 < IN_CH / 4; k4++) {
        float4 xv[4];
#pragma unroll
        for (int m = 0; m < 4; m++)
            xv[m] = *(const float4*)&Xs[(g * 4 + m) * IN_CH + k4 * 4];
        float4 wv[4];
#pragma unroll
        for (int j = 0; j < 4; j++)
            wv[j] = *(const float4*)&Ws[(k4 * 4 + j) * OUT_CH + cg * 4];
#pragma unroll
        for (int m = 0; m < 4; m++) {
            acc[m].x = fmaf(xv[m].x, wv[0].x, acc[m].x);
            acc[m].y = fmaf(xv[m].x, wv[0].y, acc[m].y);
            acc[m].z = fmaf(xv[m].x, wv[0].z, acc[m].z);
            acc[m].w = fmaf(xv[m].x, wv[0].w, acc[m].w);
            acc[m].x = fmaf(xv[m].y, wv[1].x, acc[m].x);
            acc[m].y = fmaf(xv[m].y, wv[1].y, acc[m].y);
            acc[m].z = fmaf(xv[m].y, wv[1].z, acc[m].z);
            acc[m].w = fmaf(xv[m].y, wv[1].w, acc[m].w);
            acc[m].x = fmaf(xv[m].z, wv[2].x, acc[m].x);
            acc[m].y = fmaf(xv[m].z, wv[2].y, acc[m].y);
            acc[m].z = fmaf(xv[m].z, wv[2].z, acc[m].z);
            acc[m].w = fmaf(xv[m].z, wv[2].w, acc[m].w);
            acc[m].x = fmaf(xv[m].w, wv[3].x, acc[m].x);
            acc[m].y = fmaf(xv[m].w, wv[3].y, acc[m].y);
            acc[m].z = fmaf(xv[m].w, wv[3].z, acc[m].z);
            acc[m].w = fmaf(xv[m].w, wv[3].w, acc[m].w);
        }
    }

#pragma unroll
    for (int m = 0; m < 4; m++) {
        int node = n0 + m;
        if (node < N) {
            ushort4 hv;
            hv.x = f2bf(acc[m].x);
            hv.y = f2bf(acc[m].y);
            hv.z = f2bf(acc[m].z);
            hv.w = f2bf(acc[m].w);
            *(ushort4*)&h16[(size_t)node * OUT_CH + cg * 4] = hv;
        }
        float pd = acc[m].x * att_d.x + acc[m].y * att_d.y +
                   acc[m].z * att_d.z + acc[m].w * att_d.w;
        float ps = acc[m].x * att_s.x + acc[m].y * att_s.y +
                   acc[m].z * att_s.z + acc[m].w * att_s.w;
#pragma unroll
        for (int msk = 1; msk < 16; msk <<= 1) {
            pd += __shfl_xor(pd, msk, 64);
            ps += __shfl_xor(ps, msk, 64);
        }
        if (cg == 0 && node < N) { adst[node] = pd; asrc[node] = ps; }
    }
}

// ---------- K2: per-node slot-gather softmax-aggregate + bias + L2 normalize ----------
// 1 wave/node, 2 channels/lane (ushort2), half-waves cover 2 src rows per load.
__global__ __launch_bounds__(256) void k_agg(const unsigned short* __restrict__ h16,
                                             const int* __restrict__ slots,
                                             const int* __restrict__ counts,
                                             const int* __restrict__ oflow_cnt,
                                             const int2* __restrict__ oflow,
                                             const float* __restrict__ asrc,
                                             const float* __restrict__ adst,
                                             const float* __restrict__ bias,
                                             float* __restrict__ out, int N) {
    __shared__ float2 stage[4][64];   // wave-private
    int lane = threadIdx.x & 63;
    int wid = threadIdx.x >> 6;
    int node = blockIdx.x * 4 + wid;
    if (node >= N) return;
    int half = lane >> 5;
    int ch2 = (lane & 31) * 2;

    float aD = adst[node];
    // analytic self loop (h row counted in half 0 only)
    float a = aD + asrc[node];
    a = a > 0.f ? a : NEG_SLOPE * a;
    float w_self = __expf(a);
    unsigned hv = *(const unsigned*)&h16[(size_t)node * OUT_CH + ch2];
    float wse = half ? 0.f : w_self;
    float accx = wse * __uint_as_float(hv << 16);
    float accy = wse * __uint_as_float(hv & 0xFFFF0000u);

    int c = counts[node];           // true degree (may exceed CAP)
    int cs = min(c, CAP);
    int sv = 0;
    float wv = 0.f;
    if (lane < cs) {
        sv = slots[((size_t)node << 6) + lane];   // coalesced 256B
        float av = aD + asrc[sv];                 // parallel gather (L2-hot)
        av = av > 0.f ? av : NEG_SLOPE * av;
        wv = __expf(av);                          // once per edge
    }
    float esum_lane = wv;
    stage[wid][lane] = make_float2(__int_as_float(sv), wv);

    for (int j = 0; j < cs; j += 16) {
#pragma unroll
        for (int k = 0; k < 8; k++) {
            float2 p = stage[wid][j + 2 * k + half];   // 2-addr broadcast, free
            int s = __float_as_int(p.x);
            unsigned v = *(const unsigned*)&h16[((size_t)s << 6) + ch2];
            accx = fmaf(p.y, __uint_as_float(v << 16), accx);
            accy = fmaf(p.y, __uint_as_float(v & 0xFFFF0000u), accy);
        }
    }
    // combine half-waves (even rows in lanes 0-31, odd rows in 32-63)
    accx += __shfl_xor(accx, 32, 64);
    accy += __shfl_xor(accy, 32, 64);
#pragma unroll
    for (int m = 32; m >= 1; m >>= 1) esum_lane += __shfl_xor(esum_lane, m, 64);
    float esum = esum_lane + w_self;

    // cold overflow path (oc == 0 for this input; correct if not)
    int oc = *oflow_cnt;
    if (oc > 0) {
        for (int i = 0; i < oc; i++) {
            int2 e = oflow[i];
            if (e.y == node) {
                float av = aD + asrc[e.x];
                av = av > 0.f ? av : NEG_SLOPE * av;
                float w = __expf(av);
                esum += w;
                unsigned v = *(const unsigned*)&h16[((size_t)e.x << 6) + ch2];
                accx = fmaf(w, __uint_as_float(v << 16), accx);
                accy = fmaf(w, __uint_as_float(v & 0xFFFF0000u), accy);
            }
        }
    }

    float inv = 1.f / (esum + 1e-16f);
    float2 bv = *(const float2*)&bias[ch2];
    float vx = accx * inv + bv.x;
    float vy = accy * inv + bv.y;
    float ss = vx * vx + vy * vy;
#pragma unroll
    for (int m = 16; m >= 1; m >>= 1) ss += __shfl_xor(ss, m, 64);   // within half
    float rinv = 1.f / fmaxf(sqrtf(ss), 1e-12f);
    if (!half)
        *(float2*)&out[(size_t)node * OUT_CH + ch2] = make_float2(vx * rinv, vy * rinv);
}

extern "C" void kernel_launch(void* const* d_in, const int* in_sizes, int n_in,
                              void* d_out, int out_size, void* d_ws, size_t ws_size,
                              hipStream_t stream) {
    const float* x    = (const float*)d_in[0];
    const void*  edges = d_in[1];
    const float* W    = (const float*)d_in[2];
    const float* att  = (const float*)d_in[3];
    const float* bias = (const float*)d_in[4];
    float* out = (float*)d_out;

    const int N = in_sizes[0] / IN_CH;
    const int E = in_sizes[1] / 2;
    const int NBKT = (N + BS - 1) / BS;                  // 196 buckets (<=256)
    const int MMB = (N + 63) / 64;                       // 782 mm blocks
    const int BKB = (E + CHUNK_EDGES - 1) / CHUNK_EDGES; // 196 bucket blocks
    // per-bucket capacity: mean E/NBKT=4082, sigma~64 -> 6144 is >30 sigma
    const int bcap = E / NBKT + 2048;

    char* ws = (char*)d_ws;
    size_t off = 0;
    auto alloc = [&](size_t bytes) -> void* {
        void* p = ws + off;
        off += bytes;
        off = (off + 255) & ~(size_t)255;
        return p;
    };
    // small control block (memset target): bucket_cnt[256] | oflow_cnt @256
    int*            ctrl     = (int*)alloc(320 * 4);
    int*            counts   = (int*)alloc((size_t)N * 4);         // fully written by cs
    int*            slots    = (int*)alloc((size_t)N * CAP * 4);   // 12.8 MB
    int2*           oflow    = (int2*)alloc((size_t)65536 * 8);    // stat-impossible
    unsigned short* h16      = (unsigned short*)alloc((size_t)N * OUT_CH * 2);
    float*          asrc     = (float*)alloc((size_t)N * 4);
    float*          adst     = (float*)alloc((size_t)N * 4);
    int2*           bucket   = (int2*)alloc((size_t)NBKT * bcap * 8);  // ~9.6 MB
    int*            bucket_cnt = ctrl;
    int*            oflow_cnt  = ctrl + 256;

    hipMemsetAsync(ctrl, 0, 320 * 4, stream);
    k_bucket<<<BKB, 256, 0, stream>>>(edges, E, NBKT, bucket, bcap, bucket_cnt);
    k_mm_cs<<<MMB + NBKT, 256, 0, stream>>>(x, W, att, h16, asrc, adst, N,
                                            bucket, bcap, bucket_cnt, counts,
                                            slots, oflow_cnt, oflow, MMB, NBKT);
    k_agg<<<(N + 3) / 4, 256, 0, stream>>>(h16, slots, counts, oflow_cnt, oflow,
                                           asrc, adst, bias, out, N);
}